// Round 6
// baseline (13.721 us; speedup 1.0000x reference)
//
#include <hip/hip_runtime.h>
#include <hip/hip_bf16.h>
#include <stdint.h>

#define I_DIM   256
#define O_DIM   256
#define NCH     4      // K chunks: BK=256 (=64 i-values) each

typedef float f32x4 __attribute__((ext_vector_type(4)));
typedef short bf16x8 __attribute__((ext_vector_type(8)));

// pack 2 f32 -> u32 of 2 bf16 (RNE); compiler emits v_cvt_pk_bf16_f32
__device__ __forceinline__ uint32_t pk2(float a, float b) {
    __hip_bfloat162 h = __float22bfloat162_rn(make_float2(a, b));
    uint32_t u;
    __builtin_memcpy(&u, &h, 4);
    return u;
}

// T0..T3 of clip(tanh(v)): lo = {T0=1, T1=t}, hi = {T2, T3}
__device__ __forceinline__ void basis2(float v, uint32_t& lo, uint32_t& hi) {
    const float CLIP = 0.99999994f;  // nextafter(1,0)
    float e = __expf(2.0f * v);
    float t = 1.0f - 2.0f / (e + 1.0f);
    t = fminf(CLIP, fmaxf(-CLIP, t));
    float t2 = __builtin_fmaf(2.0f * t, t, -1.0f);
    float t3 = __builtin_fmaf(2.0f * t, t2, -t);
    lo = pk2(1.0f, t);
    hi = pk2(t2, t3);
}

// Tile: BM=64 x BN=32, 8 waves, double-buffered BK=256.
// LDS: A[s] at s*32768 + row*512 + kbyte          (rows 0..63)  2x32KB
//      B[s] at 65536 + s*16384 + col*512 + kbyte  (cols 0..31)  2x16KB
// XOR swizzle ^((row&31)<<4): frag reads 2-way (free)
__global__ __launch_bounds__(512, 2) void cheby_mfma(
        const float* __restrict__ x, const float* __restrict__ cc,
        float* __restrict__ out) {
    __shared__ __align__(16) unsigned char lds[98304];

    const int tid  = threadIdx.x;
    const int lane = tid & 63;
    const int wid  = tid >> 6;          // 0..7
    const int bm   = blockIdx.x >> 3;   // 32 M-tiles
    const int bn   = blockIdx.x & 7;    // 8 N-tiles (bid&7 -> XCD-local coeff slice)
    const int m0   = bm * 64;
    const int n0   = bn * 32;

    const int arow = tid >> 3;          // 0..63  A row
    const int aiq  = tid & 7;           // 0..7   pair of x-float4s
    const int bcl  = tid & 31;          // 0..31  B col
    const int big  = tid >> 5;          // 0..15  group of 4 i's

    const float4* __restrict__ x4 = reinterpret_cast<const float4*>(x);
    const float4* __restrict__ c4 = reinterpret_cast<const float4*>(cc);

    // parity-named prefetch sets; all indices compile-time via full unroll
    float4 ax0[2], ax1[2], cb[2][4];

    auto loadAB = [&](int ch, int s) {
        const float4* p = &x4[(m0 + arow) * (I_DIM / 4) + ch * 16 + aiq * 2];
        ax0[s] = p[0]; ax1[s] = p[1];
        #pragma unroll
        for (int j = 0; j < 4; ++j)
            cb[s][j] = c4[(ch * 64 + big * 4 + j) * O_DIM + n0 + bcl];
    };

    auto stageAB = [&](int s) {
        // A: 8 x-values -> 32 bf16 -> 4 swizzled uint4 writes
        const uint32_t abase = (uint32_t)(s * 32768 + arow * 512 + aiq * 64);
        const uint32_t axr   = (uint32_t)((arow & 31) << 4);
        uint32_t w0, w1, w2, w3, w4, w5, w6, w7;
        basis2(ax0[s].x, w0, w1); basis2(ax0[s].y, w2, w3);
        basis2(ax0[s].z, w4, w5); basis2(ax0[s].w, w6, w7);
        *reinterpret_cast<uint4*>(lds + ((abase     ) ^ axr)) = make_uint4(w0, w1, w2, w3);
        *reinterpret_cast<uint4*>(lds + ((abase + 16) ^ axr)) = make_uint4(w4, w5, w6, w7);
        basis2(ax1[s].x, w0, w1); basis2(ax1[s].y, w2, w3);
        basis2(ax1[s].z, w4, w5); basis2(ax1[s].w, w6, w7);
        *reinterpret_cast<uint4*>(lds + ((abase + 32) ^ axr)) = make_uint4(w0, w1, w2, w3);
        *reinterpret_cast<uint4*>(lds + ((abase + 48) ^ axr)) = make_uint4(w4, w5, w6, w7);
        // B: 4 float4 (i = big*4..big*4+3, 4 d each) -> 2 swizzled uint4 writes
        const uint32_t bbase = (uint32_t)(65536 + s * 16384 + bcl * 512 + big * 32);
        const uint32_t bxr   = (uint32_t)((bcl & 31) << 4);
        uint32_t u0 = pk2(cb[s][0].x, cb[s][0].y);
        uint32_t u1 = pk2(cb[s][0].z, cb[s][0].w);
        uint32_t u2 = pk2(cb[s][1].x, cb[s][1].y);
        uint32_t u3 = pk2(cb[s][1].z, cb[s][1].w);
        *reinterpret_cast<uint4*>(lds + ((bbase     ) ^ bxr)) = make_uint4(u0, u1, u2, u3);
        u0 = pk2(cb[s][2].x, cb[s][2].y);
        u1 = pk2(cb[s][2].z, cb[s][2].w);
        u2 = pk2(cb[s][3].x, cb[s][3].y);
        u3 = pk2(cb[s][3].z, cb[s][3].w);
        *reinterpret_cast<uint4*>(lds + ((bbase + 16) ^ bxr)) = make_uint4(u0, u1, u2, u3);
    };

    // 8 waves: 4x2 grid of 16x16 output quadrants
    const int wr = wid >> 1, wc = wid & 1;
    const int mrow  = wr * 16 + (lane & 15);   // 0..63
    const int bcol  = wc * 16 + (lane & 15);   // 0..31
    const int klane = (lane >> 4) << 3;
    const uint32_t aswz = (uint32_t)((mrow & 31) << 4);
    const uint32_t bswz = (uint32_t)((bcol & 31) << 4);

    f32x4 acc0 = {0.f, 0.f, 0.f, 0.f};
    f32x4 acc1 = {0.f, 0.f, 0.f, 0.f};

    loadAB(0, 0);
    #pragma unroll
    for (int ch = 0; ch < NCH; ++ch) {
        const int s = ch & 1;
        if (ch + 1 < NCH) loadAB(ch + 1, s ^ 1);  // T14: issue before stage VALU
        stageAB(s);
        __syncthreads();
        const uint32_t abase = (uint32_t)(s * 32768 + mrow * 512);
        const uint32_t bbase = (uint32_t)(65536 + s * 16384 + bcol * 512);
        #pragma unroll
        for (int ks = 0; ks < 8; ++ks) {
            const uint32_t kb = (uint32_t)((ks * 32 + klane) * 2);
            bf16x8 a = *reinterpret_cast<const bf16x8*>(lds + ((abase + kb) ^ aswz));
            bf16x8 b = *reinterpret_cast<const bf16x8*>(lds + ((bbase + kb) ^ bswz));
            if (ks & 1) acc1 = __builtin_amdgcn_mfma_f32_16x16x32_bf16(a, b, acc1, 0, 0, 0);
            else        acc0 = __builtin_amdgcn_mfma_f32_16x16x32_bf16(a, b, acc0, 0, 0, 0);
        }
        // one barrier per chunk suffices with double buffering (R2 proof)
        if (ch + 1 < NCH) __syncthreads();
    }

    // C/D layout: col=lane&15, row=(lane>>4)*4+reg [m89-verified, passing since R1]
    const float sc = 1.0f / 256.0f;
    f32x4 r = acc0 + acc1;
    const int gr = m0 + wr * 16 + ((lane >> 4) << 2);
    const int gc = n0 + wc * 16 + (lane & 15);
    #pragma unroll
    for (int q = 0; q < 4; ++q)
        out[(gr + q) * O_DIM + gc] = r[q] * sc;
}

extern "C" void kernel_launch(void* const* d_in, const int* in_sizes, int n_in,
                              void* d_out, int out_size, void* d_ws, size_t ws_size,
                              hipStream_t stream) {
    (void)in_sizes; (void)n_in; (void)out_size; (void)d_ws; (void)ws_size;
    const float* x  = (const float*)d_in[0];
    const float* cc = (const float*)d_in[1];
    float* out = (float*)d_out;
    // 32 M-tiles x 8 N-tiles = 256 blocks, 512 threads (8 waves), 1 block/CU
    cheby_mfma<<<dim3(256), dim3(512), 0, stream>>>(x, cc, out);
}

// Round 7
// 12.759 us; speedup vs baseline: 1.0755x; 1.0755x over previous
//
#include <hip/hip_runtime.h>
#include <hip/hip_bf16.h>
#include <stdint.h>

#define I_DIM   256
#define O_DIM   256
#define NCH     4      // K chunks: BK=256 (=64 i-values) each

typedef float f32x4 __attribute__((ext_vector_type(4)));
typedef short bf16x8 __attribute__((ext_vector_type(8)));

// pack 2 f32 -> u32 of 2 bf16 (RNE); compiler emits v_cvt_pk_bf16_f32
__device__ __forceinline__ uint32_t pk2(float a, float b) {
    __hip_bfloat162 h = __float22bfloat162_rn(make_float2(a, b));
    uint32_t u;
    __builtin_memcpy(&u, &h, 4);
    return u;
}

// T0..T3 of tanh(v): lo = {T0=1, T1=t}, hi = {T2, T3}
// clip dropped: tanh<1 in f32 below ~9 sigma; even t=1.0 gives T_k(1)=1,
// within 5e-7 of ref's T_k(1-eps) -- far below bf16 rounding.
__device__ __forceinline__ void basis2(float v, uint32_t& lo, uint32_t& hi) {
    float e = __expf(2.0f * v);
    float t = 1.0f - 2.0f / (e + 1.0f);
    float t2 = __builtin_fmaf(2.0f * t, t, -1.0f);
    float t3 = __builtin_fmaf(2.0f * t, t2, -t);
    lo = pk2(1.0f, t);
    hi = pk2(t2, t3);
}

// LDS: A[s]: s*16384 + row*512 + kbyte ; B[s]: 32768 + s*16384 + col*512 + kbyte
// XOR-swizzled ^((row&31)<<4): frag reads 2-way (free), stage writes conflict-light
__global__ __launch_bounds__(256, 2) void cheby_mfma(
        const float* __restrict__ x, const float* __restrict__ cc,
        float* __restrict__ out) {
    __shared__ __align__(16) unsigned char lds[65536];

    const int tid  = threadIdx.x;
    const int lane = tid & 63;
    const int wid  = tid >> 6;
    const int bm   = blockIdx.x >> 3;   // 64 M-tiles
    const int bn   = blockIdx.x & 7;    // 8 N-tiles
    const int m0   = bm * 32;
    const int n0   = bn * 32;

    const int arow = tid >> 3;          // 0..31  A row
    const int aiq  = tid & 7;           // 0..7   pair of x-float4s
    const int bcl  = tid & 31;          // 0..31  B col
    const int big  = tid >> 5;          // 0..7   group of 8 i's

    const float4* __restrict__ x4 = reinterpret_cast<const float4*>(x);
    const float4* __restrict__ c4 = reinterpret_cast<const float4*>(cc);

    // parity-named prefetch sets; indices compile-time via full unroll
    float4 ax0[2], ax1[2], cb[2][8];

    auto loadAB = [&](int ch, int s) {
        const float4* p = &x4[(m0 + arow) * (I_DIM / 4) + ch * 16 + aiq * 2];
        ax0[s] = p[0]; ax1[s] = p[1];
        #pragma unroll
        for (int j = 0; j < 8; ++j)
            cb[s][j] = c4[(ch * 64 + big * 8 + j) * O_DIM + n0 + bcl];
    };

    auto stageAB = [&](int s) {
        const uint32_t abase = (uint32_t)(s * 16384 + arow * 512 + aiq * 64);
        const uint32_t axr   = (uint32_t)((arow & 31) << 4);
        uint32_t w0, w1, w2, w3, w4, w5, w6, w7;
        basis2(ax0[s].x, w0, w1); basis2(ax0[s].y, w2, w3);
        basis2(ax0[s].z, w4, w5); basis2(ax0[s].w, w6, w7);
        *reinterpret_cast<uint4*>(lds + ((abase     ) ^ axr)) = make_uint4(w0, w1, w2, w3);
        *reinterpret_cast<uint4*>(lds + ((abase + 16) ^ axr)) = make_uint4(w4, w5, w6, w7);
        basis2(ax1[s].x, w0, w1); basis2(ax1[s].y, w2, w3);
        basis2(ax1[s].z, w4, w5); basis2(ax1[s].w, w6, w7);
        *reinterpret_cast<uint4*>(lds + ((abase + 32) ^ axr)) = make_uint4(w0, w1, w2, w3);
        *reinterpret_cast<uint4*>(lds + ((abase + 48) ^ axr)) = make_uint4(w4, w5, w6, w7);
        const uint32_t bbase = (uint32_t)(32768 + s * 16384 + bcl * 512 + big * 64);
        const uint32_t bxr   = (uint32_t)((bcl & 31) << 4);
        #pragma unroll
        for (int j = 0; j < 8; j += 2) {
            uint32_t u0 = pk2(cb[s][j].x,     cb[s][j].y);
            uint32_t u1 = pk2(cb[s][j].z,     cb[s][j].w);
            uint32_t u2 = pk2(cb[s][j + 1].x, cb[s][j + 1].y);
            uint32_t u3 = pk2(cb[s][j + 1].z, cb[s][j + 1].w);
            *reinterpret_cast<uint4*>(lds + ((bbase + j * 8) ^ bxr)) = make_uint4(u0, u1, u2, u3);
        }
    };

    const int wr = wid >> 1, wc = wid & 1;
    const int mrow  = wr * 16 + (lane & 15);
    const int bcol  = wc * 16 + (lane & 15);
    const int klane = (lane >> 4) << 3;
    const uint32_t aswz = (uint32_t)((mrow & 31) << 4);
    const uint32_t bswz = (uint32_t)((bcol & 31) << 4);

    f32x4 acc0 = {0.f, 0.f, 0.f, 0.f};
    f32x4 acc1 = {0.f, 0.f, 0.f, 0.f};

    loadAB(0, 0);
    #pragma unroll
    for (int ch = 0; ch < NCH; ++ch) {
        const int s = ch & 1;
        if (ch + 1 < NCH) loadAB(ch + 1, s ^ 1);  // T14: issue before stage VALU
        stageAB(s);
        // ONE barrier per chunk: stage(ch+1) writes buf[(ch+1)&1], last read by
        // mfma(ch-1); this barrier at iter ch orders mfma(ch-1) -> stage(ch+1)
        // for every thread pair. Second barrier provably redundant.
        __syncthreads();
        const uint32_t abase = (uint32_t)(s * 16384 + mrow * 512);
        const uint32_t bbase = (uint32_t)(32768 + s * 16384 + bcol * 512);
        __builtin_amdgcn_s_setprio(1);
        #pragma unroll
        for (int ks = 0; ks < 8; ++ks) {
            const uint32_t kb = (uint32_t)((ks * 32 + klane) * 2);
            bf16x8 a = *reinterpret_cast<const bf16x8*>(lds + ((abase + kb) ^ aswz));
            bf16x8 b = *reinterpret_cast<const bf16x8*>(lds + ((bbase + kb) ^ bswz));
            if (ks & 1) acc1 = __builtin_amdgcn_mfma_f32_16x16x32_bf16(a, b, acc1, 0, 0, 0);
            else        acc0 = __builtin_amdgcn_mfma_f32_16x16x32_bf16(a, b, acc0, 0, 0, 0);
        }
        __builtin_amdgcn_s_setprio(0);
    }

    // C/D layout: col=lane&15, row=(lane>>4)*4+reg [m89-verified, passing since R1]
    const float sc = 1.0f / 256.0f;
    f32x4 r = acc0 + acc1;
    const int gr = m0 + wr * 16 + ((lane >> 4) << 2);
    const int gc = n0 + wc * 16 + (lane & 15);
    #pragma unroll
    for (int q = 0; q < 4; ++q)
        out[(gr + q) * O_DIM + gc] = r[q] * sc;
}

extern "C" void kernel_launch(void* const* d_in, const int* in_sizes, int n_in,
                              void* d_out, int out_size, void* d_ws, size_t ws_size,
                              hipStream_t stream) {
    (void)in_sizes; (void)n_in; (void)out_size; (void)d_ws; (void)ws_size;
    const float* x  = (const float*)d_in[0];
    const float* cc = (const float*)d_in[1];
    float* out = (float*)d_out;
    // 64 M-tiles x 8 N-tiles = 512 blocks, 256 threads (4 waves), 2 blocks/CU
    cheby_mfma<<<dim3(512), dim3(256), 0, stream>>>(x, cc, out);
}